// Round 6
// baseline (44.007 us; speedup 1.0000x reference)
//
#include <hip/hip_runtime.h>

// SigKernel: X (32,256,8) f32, Y (32,256,8) f32 -> out (32,32) f32.
// refinement=1.0 => interpolation identity; scale=1.0 => a_ij = dot(dX[i-1], dY[j-1]).
// Goursat PDE on 256x256 grid, boundary K[i][0]=K[0][j]=1:
//   f1 = 1 + a/2 + a^2/12, f2 = 1 - a^2/12
//   K[i][j] = (K[i][j-1] + K[i-1][j])*f1 - K[i-1][j-1]*f2 ; out = K[255][255]
//
// 1 wave per pair, lane l owns rows 4l+1..4l+4, skewed march: step s, lane l
// -> column j = s-l. Round-6: dy columns TRAVEL BY DPP (wave_shr:1) instead of
// per-step LDS reads -- the per-CU DS pipe was the round-5 bottleneck (4 waves
// x 8 ds_read_b32/step serialized). Lane 0 injects the new column each step
// from a lane-invariant broadcast ds_read_b128 pair (prefetched one step
// ahead) + cndmask. Zero-padded columns keep the branch-free identity-update
// invariant (dy=0 -> f1=f2=1 -> values frozen outside the real range).

typedef float f32x2 __attribute__((ext_vector_type(2)));
typedef float f32x4 __attribute__((ext_vector_type(4)));

#define MM    255
#define NINC  255        // dY increments 0..254 (column j uses inc j-1)
#define DYCOLS 324       // zero-padded to cover prefetch idx s+1 <= 319

static __device__ inline f32x2 fma2(f32x2 a, f32x2 b, f32x2 c) {
    return __builtin_elementwise_fma(a, b, c);
}

// up[l] = (l==0) ? 1.0f : x[l-1]  -- v_mov_b32_dpp wave_shr:1, old = 1.0
static __device__ inline float shr1_or_one(float x) {
    int r = __builtin_amdgcn_update_dpp(
        __float_as_int(1.0f), __float_as_int(x),
        0x138 /* wave_shr:1 */, 0xF, 0xF, false);
    return __int_as_float(r);
}

// y[l] = x[l-1] for l>0; lane 0 keeps its old value (fixed by cndmask after).
static __device__ inline float shr1_keep(float x) {
    int r = __builtin_amdgcn_update_dpp(
        __float_as_int(x), __float_as_int(x),
        0x138 /* wave_shr:1 */, 0xF, 0xF, false);
    return __int_as_float(r);
}

__global__ __launch_bounds__(64) void sigker_dppstream(
    const float* __restrict__ X,
    const float* __restrict__ Y,
    float* __restrict__ out)
{
    const int pair = blockIdx.x;      // 0..1023
    const int ax = pair >> 5;
    const int by = pair & 31;
    const int l  = threadIdx.x;       // 0..63

    __shared__ f32x4 dYv[DYCOLS * 2]; // inc j at dYv[2j], dYv[2j+1] (32B/col)

    const float* Xa = X + ax * 2048;
    const float* Yb = Y + by * 2048;

    // Zero the padded tail (inc 255..323).
    for (int v = l; v < (DYCOLS - NINC) * 2; v += 64)
        dYv[NINC * 2 + v] = (f32x4){0, 0, 0, 0};

    // Stage dY increments: lane l computes inc rows 4l..4l+3 (mask >= 255).
    {
        f32x4 g[10];
        const f32x4* Yv = (const f32x4*)(Yb + l * 32);
        #pragma unroll
        for (int k = 0; k < 8; ++k) g[k] = Yv[k];
        g[8] = (l < 63) ? Yv[8] : (f32x4){0, 0, 0, 0};
        g[9] = (l < 63) ? Yv[9] : (f32x4){0, 0, 0, 0};
        #pragma unroll
        for (int r = 0; r < 4; ++r) {
            const int ji = 4 * l + r;
            if (ji < NINC) {
                f32x4 d0, d1;
                #pragma unroll
                for (int c = 0; c < 4; ++c) {
                    const int e = r * 8 + c;
                    d0[c] = g[(e + 8) >> 2][(e + 8) & 3] - g[e >> 2][e & 3];
                }
                #pragma unroll
                for (int c = 4; c < 8; ++c) {
                    const int e = r * 8 + c;
                    d1[c - 4] = g[(e + 8) >> 2][(e + 8) & 3] - g[e >> 2][e & 3];
                }
                dYv[2 * ji]     = d0;
                dYv[2 * ji + 1] = d1;
            }
        }
    }

    // dx rows 4l+1..4l+4 from contiguous window [4l*8, 4l*8+40) of Xa.
    f32x2 dxp0[8], dxp1[8];   // {r0,r1}, {r2,r3} per dim
    {
        f32x4 f[10];
        const f32x4* Xv = (const f32x4*)(Xa + l * 32);
        #pragma unroll
        for (int k = 0; k < 8; ++k) f[k] = Xv[k];
        f[8] = (l < 63) ? Xv[8] : (f32x4){0, 0, 0, 0};
        f[9] = (l < 63) ? Xv[9] : (f32x4){0, 0, 0, 0};
        #pragma unroll
        for (int c = 0; c < 8; ++c) {
            const float e0 = f[(c)      >> 2][(c)      & 3];
            const float e1 = f[(8 + c)  >> 2][(8 + c)  & 3];
            const float e2 = f[(16 + c) >> 2][(16 + c) & 3];
            const float e3 = f[(24 + c) >> 2][(24 + c) & 3];
            const float e4 = f[(32 + c) >> 2][(32 + c) & 3];
            dxp0[c] = (f32x2){e1 - e0, e2 - e1};
            dxp1[c] = (f32x2){e3 - e2, e4 - e3};
        }
    }
    __syncthreads();

    const f32x2 C12  = { 1.0f / 12.0f,  1.0f / 12.0f};
    const f32x2 CN12 = {-1.0f / 12.0f, -1.0f / 12.0f};
    const f32x2 CH   = { 0.5f, 0.5f};
    const f32x2 C1   = { 1.0f, 1.0f};

    float dy0, dy1, dy2, dy3, dy4, dy5, dy6, dy7;
    f32x2 f1a, f1b, f2a, f2b;

    auto factors = [&]() {
        f32x2 b = (f32x2){dy0, dy0};
        f32x2 a01 = dxp0[0] * b, a23 = dxp1[0] * b;
        b = (f32x2){dy1, dy1}; a01 = fma2(dxp0[1], b, a01); a23 = fma2(dxp1[1], b, a23);
        b = (f32x2){dy2, dy2}; a01 = fma2(dxp0[2], b, a01); a23 = fma2(dxp1[2], b, a23);
        b = (f32x2){dy3, dy3}; a01 = fma2(dxp0[3], b, a01); a23 = fma2(dxp1[3], b, a23);
        b = (f32x2){dy4, dy4}; a01 = fma2(dxp0[4], b, a01); a23 = fma2(dxp1[4], b, a23);
        b = (f32x2){dy5, dy5}; a01 = fma2(dxp0[5], b, a01); a23 = fma2(dxp1[5], b, a23);
        b = (f32x2){dy6, dy6}; a01 = fma2(dxp0[6], b, a01); a23 = fma2(dxp1[6], b, a23);
        b = (f32x2){dy7, dy7}; a01 = fma2(dxp0[7], b, a01); a23 = fma2(dxp1[7], b, a23);
        const f32x2 q01 = a01 * a01, q23 = a23 * a23;
        f1a = fma2(q01, C12, fma2(a01, CH, C1));
        f1b = fma2(q23, C12, fma2(a23, CH, C1));
        f2a = fma2(q01, CN12, C1);
        f2b = fma2(q23, CN12, C1);
    };

    const bool isL0 = (l == 0);

    // Init for step 1: lane 0 holds col 1 (= inc 0), other lanes 0.
    {
        const f32x4 i0 = dYv[0], i1 = dYv[1];
        dy0 = isL0 ? i0.x : 0.0f; dy1 = isL0 ? i0.y : 0.0f;
        dy2 = isL0 ? i0.z : 0.0f; dy3 = isL0 ? i0.w : 0.0f;
        dy4 = isL0 ? i1.x : 0.0f; dy5 = isL0 ? i1.y : 0.0f;
        dy6 = isL0 ? i1.z : 0.0f; dy7 = isL0 ? i1.w : 0.0f;
    }
    factors();                         // factors for step 1

    // bc = inc[s] (injected as col s+1 at end of step s); init inc[1].
    f32x4 bcA = dYv[2], bcB = dYv[3];

    float K0 = 1.0f, K1 = 1.0f, K2 = 1.0f, K3 = 1.0f, upd = 1.0f;

    #pragma unroll 2
    for (int s = 1; s <= MM + 63; ++s) {     // 318 steps
        // Prefetch inc[s+1] (broadcast: lane-invariant address).
        const f32x4 nA = dYv[2 * s + 2];
        const f32x4 nB = dYv[2 * s + 3];

        // --- recurrence for step s (factors ready) ---
        const float up = shr1_or_one(K3);
        const float t0 = upd * f2a.x;
        const float t1 = K0  * f2a.y;
        const float t2 = K1  * f2b.x;
        const float t3 = K2  * f2b.y;
        const float c0 = fmaf(K0, f1a.x, -t0);
        const float c1 = fmaf(K1, f1a.y, -t1);
        const float c2 = fmaf(K2, f1b.x, -t2);
        const float c3 = fmaf(K3, f1b.y, -t3);
        const float k0 = fmaf(up, f1a.x, c0);
        const float k1 = fmaf(k0, f1a.y, c1);
        const float k2 = fmaf(k1, f1b.x, c2);
        const float k3 = fmaf(k2, f1b.y, c3);
        upd = up; K0 = k0; K1 = k1; K2 = k2; K3 = k3;

        // --- transport dy up one lane; lane 0 takes the injected column ---
        dy0 = shr1_keep(dy0); dy1 = shr1_keep(dy1);
        dy2 = shr1_keep(dy2); dy3 = shr1_keep(dy3);
        dy4 = shr1_keep(dy4); dy5 = shr1_keep(dy5);
        dy6 = shr1_keep(dy6); dy7 = shr1_keep(dy7);
        dy0 = isL0 ? bcA.x : dy0; dy1 = isL0 ? bcA.y : dy1;
        dy2 = isL0 ? bcA.z : dy2; dy3 = isL0 ? bcA.w : dy3;
        dy4 = isL0 ? bcB.x : dy4; dy5 = isL0 ? bcB.y : dy5;
        dy6 = isL0 ? bcB.z : dy6; dy7 = isL0 ? bcB.w : dy7;

        // --- factors for step s+1 ---
        factors();

        bcA = nA; bcB = nB;
    }

    // Row 255 = lane 63, local r=2; last real update at s=318 (j=255).
    if (l == 63) out[pair] = K2;
}

extern "C" void kernel_launch(void* const* d_in, const int* in_sizes, int n_in,
                              void* d_out, int out_size, void* d_ws, size_t ws_size,
                              hipStream_t stream)
{
    const float* X = (const float*)d_in[0];
    const float* Y = (const float*)d_in[1];
    float* out = (float*)d_out;
    (void)in_sizes; (void)n_in; (void)out_size; (void)d_ws; (void)ws_size;

    sigker_dppstream<<<dim3(32 * 32), dim3(64), 0, stream>>>(X, Y, out);
}

// Round 7
// 42.332 us; speedup vs baseline: 1.0396x; 1.0396x over previous
//
#include <hip/hip_runtime.h>

// SigKernel: X (32,256,8) f32, Y (32,256,8) f32 -> out (32,32) f32.
// refinement=1.0 => interpolation identity; scale=1.0 => a_ij = dot(dX[i-1], dY[j-1]).
// Goursat PDE on 256x256 grid, boundary K[i][0]=K[0][j]=1:
//   f1 = 1 + a/2 + a^2/12, f2 = 1 - a^2/12
//   K[i][j] = (K[i][j-1] + K[i-1][j])*f1 - K[i-1][j-1]*f2 ; out = K[255][255]
//
// 1 wave per pair, lane l owns rows 4l+1..4l+4, skewed march: step s, lane l
// -> column j = s-l. dy columns travel lane-to-lane by DPP wave_shr:1; the
// new column is injected at lane 0 via the DPP *old* operand (lane 0 is the
// invalid-source lane under wave_shr with bound_ctrl=0 -> keeps old), fed by
// a lane-invariant broadcast ds_read_b128 pair prefetched one step ahead.
// Dot products use inline-asm v_pk_fma_f32 with op_sel/op_sel_hi broadcast of
// the dy halves -- no operand-packing movs (the round-6 hidden cost).
// Zero-padded columns keep the branch-free identity-update invariant.

typedef float f32x2 __attribute__((ext_vector_type(2)));
typedef float f32x4 __attribute__((ext_vector_type(4)));

#define MM     255
#define NINC   255       // dY increments 0..254 (column j uses inc j-1)
#define DYCOLS 324       // padded: max read idx 2*318+3 = 639 < 648

static __device__ inline f32x2 fma2(f32x2 a, f32x2 b, f32x2 c) {
    return __builtin_elementwise_fma(a, b, c);
}

// dst[l] = (l==0) ? old : x[l-1]   (wave_shr:1, bound_ctrl=0 keeps old at l=0;
// 'old' must be lane-invariant for the inject use). HW-verified rounds 5/6.
static __device__ inline float dpp_shr1(float old, float x) {
    int r = __builtin_amdgcn_update_dpp(
        __float_as_int(old), __float_as_int(x),
        0x138 /* wave_shr:1 */, 0xF, 0xF, false);
    return __int_as_float(r);
}

// d = a * {b.lo, b.lo}
static __device__ inline void pk_mul_bl(f32x2& d, f32x2 a, f32x2 b) {
    asm("v_pk_mul_f32 %0, %1, %2 op_sel:[0,0] op_sel_hi:[1,0]"
        : "=v"(d) : "v"(a), "v"(b));
}
// d += a * {b.lo, b.lo}
static __device__ inline void pk_fma_bl(f32x2& d, f32x2 a, f32x2 b) {
    asm("v_pk_fma_f32 %0, %1, %2, %0 op_sel:[0,0,0] op_sel_hi:[1,0,1]"
        : "+v"(d) : "v"(a), "v"(b));
}
// d += a * {b.hi, b.hi}
static __device__ inline void pk_fma_bh(f32x2& d, f32x2 a, f32x2 b) {
    asm("v_pk_fma_f32 %0, %1, %2, %0 op_sel:[0,1,0] op_sel_hi:[1,1,1]"
        : "+v"(d) : "v"(a), "v"(b));
}

__global__ __launch_bounds__(64) void sigker_opsel(
    const float* __restrict__ X,
    const float* __restrict__ Y,
    float* __restrict__ out)
{
    const int pair = blockIdx.x;      // 0..1023
    const int ax = pair >> 5;
    const int by = pair & 31;
    const int l  = threadIdx.x;       // 0..63

    __shared__ f32x4 dYv[DYCOLS * 2]; // inc j at dYv[2j], dYv[2j+1]

    const float* Xa = X + ax * 2048;
    const float* Yb = Y + by * 2048;

    // Zero the padded tail (inc 255..323).
    for (int v = l; v < (DYCOLS - NINC) * 2; v += 64)
        dYv[NINC * 2 + v] = (f32x4){0, 0, 0, 0};

    // Stage dY increments: lane l computes inc rows 4l..4l+3.
    {
        f32x4 g[10];
        const f32x4* Yv = (const f32x4*)(Yb + l * 32);
        #pragma unroll
        for (int k = 0; k < 8; ++k) g[k] = Yv[k];
        g[8] = (l < 63) ? Yv[8] : (f32x4){0, 0, 0, 0};
        g[9] = (l < 63) ? Yv[9] : (f32x4){0, 0, 0, 0};
        #pragma unroll
        for (int r = 0; r < 4; ++r) {
            const int ji = 4 * l + r;
            if (ji < NINC) {
                f32x4 d0, d1;
                #pragma unroll
                for (int c = 0; c < 4; ++c) {
                    const int e = r * 8 + c;
                    d0[c] = g[(e + 8) >> 2][(e + 8) & 3] - g[e >> 2][e & 3];
                }
                #pragma unroll
                for (int c = 4; c < 8; ++c) {
                    const int e = r * 8 + c;
                    d1[c - 4] = g[(e + 8) >> 2][(e + 8) & 3] - g[e >> 2][e & 3];
                }
                dYv[2 * ji]     = d0;
                dYv[2 * ji + 1] = d1;
            }
        }
    }

    // dx rows 4l+1..4l+4: dxp0[c] = {dx_r0[c], dx_r1[c]}, dxp1[c] = {r2,r3}.
    f32x2 dxp0[8], dxp1[8];
    {
        f32x4 f[10];
        const f32x4* Xv = (const f32x4*)(Xa + l * 32);
        #pragma unroll
        for (int k = 0; k < 8; ++k) f[k] = Xv[k];
        f[8] = (l < 63) ? Xv[8] : (f32x4){0, 0, 0, 0};
        f[9] = (l < 63) ? Xv[9] : (f32x4){0, 0, 0, 0};
        #pragma unroll
        for (int c = 0; c < 8; ++c) {
            const float e0 = f[(c)      >> 2][(c)      & 3];
            const float e1 = f[(8 + c)  >> 2][(8 + c)  & 3];
            const float e2 = f[(16 + c) >> 2][(16 + c) & 3];
            const float e3 = f[(24 + c) >> 2][(24 + c) & 3];
            const float e4 = f[(32 + c) >> 2][(32 + c) & 3];
            dxp0[c] = (f32x2){e1 - e0, e2 - e1};
            dxp1[c] = (f32x2){e3 - e2, e4 - e3};
        }
    }
    __syncthreads();

    const f32x2 C12  = { 1.0f / 12.0f,  1.0f / 12.0f};
    const f32x2 CN12 = {-1.0f / 12.0f, -1.0f / 12.0f};
    const f32x2 CH   = { 0.5f, 0.5f};
    const f32x2 C1   = { 1.0f, 1.0f};

    // dy column in 4 natural pairs: dyp[0]={dy0,dy1} .. dyp[3]={dy6,dy7}.
    f32x2 dyp[4];
    f32x2 f1a, f1b, f2a, f2b;

    auto factors = [&]() {
        f32x2 a01, a23;
        pk_mul_bl(a01, dxp0[0], dyp[0]);  pk_mul_bl(a23, dxp1[0], dyp[0]);
        pk_fma_bh(a01, dxp0[1], dyp[0]);  pk_fma_bh(a23, dxp1[1], dyp[0]);
        pk_fma_bl(a01, dxp0[2], dyp[1]);  pk_fma_bl(a23, dxp1[2], dyp[1]);
        pk_fma_bh(a01, dxp0[3], dyp[1]);  pk_fma_bh(a23, dxp1[3], dyp[1]);
        pk_fma_bl(a01, dxp0[4], dyp[2]);  pk_fma_bl(a23, dxp1[4], dyp[2]);
        pk_fma_bh(a01, dxp0[5], dyp[2]);  pk_fma_bh(a23, dxp1[5], dyp[2]);
        pk_fma_bl(a01, dxp0[6], dyp[3]);  pk_fma_bl(a23, dxp1[6], dyp[3]);
        pk_fma_bh(a01, dxp0[7], dyp[3]);  pk_fma_bh(a23, dxp1[7], dyp[3]);
        const f32x2 q01 = a01 * a01, q23 = a23 * a23;
        f1a = fma2(q01, C12, fma2(a01, CH, C1));
        f1b = fma2(q23, C12, fma2(a23, CH, C1));
        f2a = fma2(q01, CN12, C1);
        f2b = fma2(q23, CN12, C1);
    };

    // Init for step 1: lane 0 holds col 1 (= inc 0), other lanes 0.
    {
        const bool isL0 = (l == 0);
        const f32x4 i0 = dYv[0], i1 = dYv[1];
        dyp[0] = isL0 ? (f32x2){i0.x, i0.y} : (f32x2){0, 0};
        dyp[1] = isL0 ? (f32x2){i0.z, i0.w} : (f32x2){0, 0};
        dyp[2] = isL0 ? (f32x2){i1.x, i1.y} : (f32x2){0, 0};
        dyp[3] = isL0 ? (f32x2){i1.z, i1.w} : (f32x2){0, 0};
    }
    factors();                          // factors for step 1

    // bc = inc[s], injected as column s+1 at end of step s; init inc[1].
    f32x4 bcA = dYv[2], bcB = dYv[3];
    const f32x4* pf = &dYv[4];          // prefetch cursor: inc[s+1] at step s

    float K0 = 1.0f, K1 = 1.0f, K2 = 1.0f, K3 = 1.0f, upd = 1.0f;

    #pragma unroll 2
    for (int s = 1; s <= MM + 63; ++s) {     // 318 steps
        // Prefetch inc[s+1] (lane-invariant broadcast reads).
        const f32x4 nA = pf[0];
        const f32x4 nB = pf[1];
        pf += 2;

        // --- recurrence for step s (factors ready from previous iter) ---
        const float up = dpp_shr1(1.0f, K3);
        const float t0 = upd * f2a.x;
        const float t1 = K0  * f2a.y;
        const float t2 = K1  * f2b.x;
        const float t3 = K2  * f2b.y;
        const float c0 = fmaf(K0, f1a.x, -t0);
        const float c1 = fmaf(K1, f1a.y, -t1);
        const float c2 = fmaf(K2, f1b.x, -t2);
        const float c3 = fmaf(K3, f1b.y, -t3);
        const float k0 = fmaf(up, f1a.x, c0);
        const float k1 = fmaf(k0, f1a.y, c1);
        const float k2 = fmaf(k1, f1b.x, c2);
        const float k3 = fmaf(k2, f1b.y, c3);
        upd = up; K0 = k0; K1 = k1; K2 = k2; K3 = k3;

        // --- transport dy up one lane; lane 0 takes bc via the dpp 'old' ---
        dyp[0].x = dpp_shr1(bcA.x, dyp[0].x);
        dyp[0].y = dpp_shr1(bcA.y, dyp[0].y);
        dyp[1].x = dpp_shr1(bcA.z, dyp[1].x);
        dyp[1].y = dpp_shr1(bcA.w, dyp[1].y);
        dyp[2].x = dpp_shr1(bcB.x, dyp[2].x);
        dyp[2].y = dpp_shr1(bcB.y, dyp[2].y);
        dyp[3].x = dpp_shr1(bcB.z, dyp[3].x);
        dyp[3].y = dpp_shr1(bcB.w, dyp[3].y);

        // --- factors for step s+1 ---
        factors();

        bcA = nA; bcB = nB;
    }

    // Row 255 = lane 63, local r=2; last real update at s=318 (j=255).
    if (l == 63) out[pair] = K2;
}

extern "C" void kernel_launch(void* const* d_in, const int* in_sizes, int n_in,
                              void* d_out, int out_size, void* d_ws, size_t ws_size,
                              hipStream_t stream)
{
    const float* X = (const float*)d_in[0];
    const float* Y = (const float*)d_in[1];
    float* out = (float*)d_out;
    (void)in_sizes; (void)n_in; (void)out_size; (void)d_ws; (void)ws_size;

    sigker_opsel<<<dim3(32 * 32), dim3(64), 0, stream>>>(X, Y, out);
}